// Round 14
// baseline (137.696 us; speedup 1.0000x reference)
//
#include <hip/hip_runtime.h>
#include <hip/hip_bf16.h>

typedef __attribute__((ext_vector_type(8))) short short8;
typedef __attribute__((ext_vector_type(16))) float floatx16;
typedef __attribute__((ext_vector_type(4))) float floatx4;
typedef __attribute__((ext_vector_type(4))) unsigned uintx4;

__device__ __forceinline__ short f2bf(float f) {
    unsigned u = __builtin_bit_cast(unsigned, f);
    u += 0x7fffu + ((u >> 16) & 1u);   // RNE
    return (short)(u >> 16);
}

__device__ __forceinline__ unsigned pk_bf16(float lo, float hi) {
    unsigned short a = __builtin_bit_cast(unsigned short, (__bf16)lo);
    unsigned short b = __builtin_bit_cast(unsigned short, (__bf16)hi);
    return (unsigned)a | ((unsigned)b << 16);
}

__device__ __forceinline__ void gload_lds16(const void* g, void* l) {
    __builtin_amdgcn_global_load_lds(
        (const __attribute__((address_space(1))) unsigned*)g,
        (__attribute__((address_space(3))) unsigned*)l, 16, 0, 0);
}

// ---------------------------------------------------------------------------
// f32 -> bf16 convert for x, Wq/Wk/Wv, Wo — one launch. 32-col-tile XOR
// swizzle (GEMM operand layout): chunk cc of dest row holds src chunk cc^(row&3).
__global__ __launch_bounds__(256)
void conv_all(const float* __restrict__ x, const float* __restrict__ Wq,
              const float* __restrict__ Wk, const float* __restrict__ Wv,
              const float* __restrict__ Wo, short* __restrict__ xb,
              short* __restrict__ wqkv, short* __restrict__ wob) {
    const int bid = blockIdx.x;                // 0..7167
    const float* src; short* dst; int srow, drow;
    if (bid < 2048)      { src = x;  dst = xb;  srow = bid;        drow = bid; }
    else if (bid < 5120) {
        int r = bid - 2048;
        dst = wqkv; drow = r;
        if (r < 2048)      { src = Wq; srow = r; }
        else if (r < 2560) { src = Wk; srow = r - 2048; }
        else               { src = Wv; srow = r - 2560; }
    } else               { src = Wo; dst = wob; srow = bid - 5120; drow = srow; }
    const int c = threadIdx.x;
    const int kt = c >> 2, cc = c & 3;
    const float* s = src + (size_t)srow * 2048 + kt * 32 + (cc ^ (drow & 3)) * 8;
    float4 v0 = *(const float4*)s;
    float4 v1 = *(const float4*)(s + 4);
    short8 o = { f2bf(v0.x), f2bf(v0.y), f2bf(v0.z), f2bf(v0.w),
                 f2bf(v1.x), f2bf(v1.y), f2bf(v1.z), f2bf(v1.w) };
    *(short8*)(dst + (size_t)drow * 2048 + kt * 32 + cc * 8) = o;
}

// ---------------------------------------------------------------------------
// 8-wave double-buffered bf16 GEMM, BK=32, VGPR-capped for 8 waves/EU
// (32 waves/CU). 32-col-group operand swizzle (chunk ^ (row&3)).
// EPI 0: QKV epilogue (qb pre-scaled; kb/vt attn-swizzled). EPI 1: f32 + bias.
template<int BN, int EPI>
__global__ __launch_bounds__(512, 8)
void gemm8(const short* __restrict__ A, const short* __restrict__ Bw,
           short* __restrict__ qb, short* __restrict__ kb, short* __restrict__ vt,
           float* __restrict__ fout, const float* __restrict__ bias) {
    constexpr int K = 2048;
    constexpr int NN = BN / 32;
    constexpr int ACH = 128 * 4;               // A 16B-chunks per slab
    constexpr int NCH = (128 + BN) * 4;        // total chunks per slab
    constexpr int NIT = K / 32;
    __shared__ short sm[2][(128 + BN) * 32];

    const int t = threadIdx.x, lane = t & 63, w = t >> 6;
    const int wm = w & 3, wn = w >> 2;
    const int l15 = lane & 15, lh = lane >> 4;
    const int bn = blockIdx.x, bm = blockIdx.y;
    const int ra0 = bm * 128;
    const short* Bbase = Bw + (size_t)bn * BN * K;

    floatx4 acc[2][NN] = {};

    auto stage = [&](int buf, int k0) {
        short* base = &sm[buf][0];
        #pragma unroll
        for (int i = 0; i < 2; ++i) {
            int c = i * 512 + t;
            if (c < NCH) {
                if (c < ACH) {
                    int row = c >> 2, cc = c & 3;
                    gload_lds16(A + (size_t)(ra0 + row) * K + k0 + cc * 8, base + c * 8);
                } else {
                    int c2 = c - ACH;
                    int row = c2 >> 2, cc = c2 & 3;
                    gload_lds16(Bbase + (size_t)row * K + k0 + cc * 8, base + (ACH + c2) * 8);
                }
            }
        }
    };

    stage(0, 0);
    #pragma unroll 1
    for (int it = 0; it < NIT; ++it) {
        __syncthreads();                       // slab `it` ready
        if (it + 1 < NIT) stage((it + 1) & 1, (it + 1) * 32);
        const short* As = &sm[it & 1][0];
        const short* Bs = As + 128 * 32;
        short8 a[2], b[NN];
        #pragma unroll
        for (int m = 0; m < 2; ++m) {
            int arow = wm * 32 + m * 16 + l15;
            a[m] = *(const short8*)(As + arow * 32 + ((lh ^ (arow & 3)) << 3));
        }
        #pragma unroll
        for (int n = 0; n < NN; ++n) {
            int brow = wn * (BN / 2) + n * 16 + l15;
            b[n] = *(const short8*)(Bs + brow * 32 + ((lh ^ (brow & 3)) << 3));
        }
        #pragma unroll
        for (int m = 0; m < 2; ++m)
            #pragma unroll
            for (int n = 0; n < NN; ++n)
                acc[m][n] = __builtin_amdgcn_mfma_f32_16x16x32_bf16(a[m], b[n], acc[m][n], 0, 0, 0);
    }

    #pragma unroll
    for (int m = 0; m < 2; ++m) {
        #pragma unroll
        for (int n = 0; n < NN; ++n) {
            #pragma unroll
            for (int r = 0; r < 4; ++r) {
                int row = ra0 + wm * 32 + m * 16 + lh * 4 + r;
                int col = bn * BN + wn * (BN / 2) + n * 16 + l15;
                float v = acc[m][n][r];
                if constexpr (EPI == 1) {
                    fout[(size_t)row * 2048 + col] = v + bias[col];
                } else {
                    if (col < 2048) {
                        qb[(size_t)row * 2048 + col] = f2bf(v * 0.18033688011112042f);
                    } else if (col < 2560) {
                        int kcol = col - 2048, within = kcol & 63;
                        int cp = ((within >> 3) ^ (row & 7)) & 7;
                        kb[(size_t)row * 512 + (kcol & ~63) + (cp << 3) + (within & 7)] = f2bf(v);
                    } else {
                        int dg = col - 2560;
                        int cp = (((row >> 3) & 7) ^ (dg & 7)) & 7;
                        vt[(size_t)dg * 2048 + (row & ~63) + (cp << 3) + (row & 7)] = f2bf(v);
                    }
                }
            }
        }
    }
}

// ---------------------------------------------------------------------------
// Causal GQA attention (round-13 proven kernel; only the O-writeout swizzle
// switches to the 32-col GEMM-A scheme). 8 waves = 4 q-strips x kv-parity;
// pair {i, 31-i}; 128-kv-row slabs double-buffered; one barrier per slab;
// parity partials merged via LDS. hq = blockIdx.x -> XCD-local KV (L2-fit).
__global__ __launch_bounds__(512, 4)
void attn_fwd(const short* __restrict__ qb, const short* __restrict__ kb,
              const short* __restrict__ vt, short* __restrict__ ob) {
    __shared__ __align__(16) short smem[2][16384];  // per buf: K 128x64 | V^T 64x128

    const int t = threadIdx.x, lane = t & 63, w = t >> 6;
    const int l31 = lane & 31, hi = lane >> 5;
    const int hq = blockIdx.x, hk = hq >> 2;   // XCD-local head placement
    const int pairi = blockIdx.y;              // 0..15
    const int qtA = pairi, qtB = 31 - pairi;
    const int a = w >> 1, p = w & 1;           // strip 0..3, kv parity
    const int s = a & 1;
    const int myqt = (a < 2) ? qtA : qtB;
    const int q0 = myqt * 64 + s * 32;
    const int rg = q0 + l31;                   // this lane's q row
    const int swl = l31 & 7;

    short8 qf[4];
    {
        const short* qrow = qb + (size_t)rg * 2048 + hq * 64;
        #pragma unroll
        for (int kk = 0; kk < 4; ++kk)
            qf[kk] = *(const short8*)(qrow + kk * 16 + hi * 8);
    }

    float m = -3e38f, l = 0.f;
    floatx16 acc[2] = {};

    auto stage = [&](int buf, int j0) {        // j0 = slab base kv-row
        short* base = &smem[buf][0];
        #pragma unroll
        for (int i = 0; i < 4; ++i) {
            int c = i * 512 + t;
            if (i < 2) {                       // K chunks 0..1023
                int row = c >> 3, cc = c & 7;
                gload_lds16(kb + (size_t)(j0 + row) * 512 + hk * 64 + cc * 8, base + c * 8);
            } else {                           // V chunks 1024..2047
                int cv = c - 1024, drow = cv >> 4, cc = cv & 15;
                gload_lds16(vt + (size_t)(hk * 64 + drow) * 2048 + j0 + cc * 8, base + c * 8);
            }
        }
    };

    const int nss = (qtB >> 1) + 1;
    stage(0, 0);
    #pragma unroll 1
    for (int ss = 0; ss < nss; ++ss) {
        __syncthreads();                       // slab ss ready
        if (ss + 1 < nss) stage((ss + 1) & 1, (ss + 1) * 128);
        const int kt = 2 * ss + p;
        if (kt <= myqt) {
            const short* K0 = &smem[ss & 1][0];
            const short* V0 = &smem[ss & 1][8192];

            // ---- S^T = K . Q^T (2 kv-blocks x 4 k-steps)
            floatx16 sT[2];
            #pragma unroll
            for (int kb2 = 0; kb2 < 2; ++kb2) {
                floatx16 acc2 = {};
                const int row = p * 64 + kb2 * 32 + l31;
                #pragma unroll
                for (int kk = 0; kk < 4; ++kk) {
                    short8 kf = *(const short8*)(K0 + row * 64 + (((2 * kk + hi) ^ swl) << 3));
                    acc2 = __builtin_amdgcn_mfma_f32_32x32x16_bf16(kf, qf[kk], acc2, 0, 0, 0);
                }
                sT[kb2] = acc2;
            }

            // ---- causal mask (diagonal tile only)
            if (kt == myqt) {
                #pragma unroll
                for (int kb2 = 0; kb2 < 2; ++kb2)
                    #pragma unroll
                    for (int r = 0; r < 16; ++r) {
                        int jg = kt * 64 + kb2 * 32 + (r & 3) + 8 * (r >> 2) + 4 * hi;
                        if (jg > rg) sT[kb2][r] = -3e38f;
                    }
            }

            // ---- row max
            float v[16];
            #pragma unroll
            for (int r = 0; r < 16; ++r) v[r] = fmaxf(sT[0][r], sT[1][r]);
            #pragma unroll
            for (int st = 8; st >= 1; st >>= 1)
                #pragma unroll
                for (int r = 0; r < 8; ++r)
                    if (r < st) v[r] = fmaxf(v[r], v[r + st]);
            float tm = fmaxf(v[0], __shfl_xor(v[0], 32));

            // ---- defer-max
            if (!__all(tm <= m + 8.0f)) {
                float mn = fmaxf(m, tm);
                float sf = __builtin_amdgcn_exp2f(m - mn);
                m = mn;
                l *= sf;
                #pragma unroll
                for (int n = 0; n < 2; ++n)
                    #pragma unroll
                    for (int r = 0; r < 16; ++r) acc[n][r] *= sf;
            }

            // ---- p = exp2(s - m), row sum
            float sv[16];
            #pragma unroll
            for (int kb2 = 0; kb2 < 2; ++kb2)
                #pragma unroll
                for (int r = 0; r < 16; ++r)
                    sT[kb2][r] = __builtin_amdgcn_exp2f(sT[kb2][r] - m);
            #pragma unroll
            for (int r = 0; r < 16; ++r) sv[r] = sT[0][r] + sT[1][r];
            #pragma unroll
            for (int st = 8; st >= 1; st >>= 1)
                #pragma unroll
                for (int r = 0; r < 8; ++r)
                    if (r < st) sv[r] += sv[r + st];
            l += sv[0] + __shfl_xor(sv[0], 32);

            // ---- P^T -> B-fragments (cvt_pk + cross-half exchange), then PV
            #pragma unroll
            for (int kb2 = 0; kb2 < 2; ++kb2) {
                unsigned Qd[8], Pd[8];
                #pragma unroll
                for (int c = 0; c < 8; ++c)
                    Qd[c] = pk_bf16(sT[kb2][2 * c], sT[kb2][2 * c + 1]);
                #pragma unroll
                for (int c = 0; c < 8; ++c)
                    Pd[c] = __shfl_xor(Qd[c], 32);
                #pragma unroll
                for (int b = 0; b < 2; ++b) {
                    uintx4 j;
                    if (b == 0) {
                        j.x = hi ? Pd[2] : Qd[0];
                        j.y = hi ? Pd[3] : Qd[1];
                        j.z = hi ? Qd[2] : Pd[0];
                        j.w = hi ? Qd[3] : Pd[1];
                    } else {
                        j.x = hi ? Pd[6] : Qd[4];
                        j.y = hi ? Pd[7] : Qd[5];
                        j.z = hi ? Qd[6] : Pd[4];
                        j.w = hi ? Qd[7] : Pd[5];
                    }
                    short8 pf = __builtin_bit_cast(short8, j);
                    const int kk = kb2 * 2 + b;
                    const int ch = p * 64 + (((2 * kk + hi) ^ swl) << 3);
                    short8 vf0 = *(const short8*)(V0 + l31 * 128 + ch);
                    acc[0] = __builtin_amdgcn_mfma_f32_32x32x16_bf16(vf0, pf, acc[0], 0, 0, 0);
                    short8 vf1 = *(const short8*)(V0 + (32 + l31) * 128 + ch);
                    acc[1] = __builtin_amdgcn_mfma_f32_32x32x16_bf16(vf1, pf, acc[1], 0, 0, 0);
                }
            }
        }
    }

    // ---- merge the two kv-parity partials per strip (lane = q column)
    __syncthreads();                           // all compute done; reuse smem
    float* mb = (float*)&smem[0][0] + ((size_t)a * 64 + lane) * 34;
    if (p == 1) {
        #pragma unroll
        for (int n = 0; n < 2; ++n)
            #pragma unroll
            for (int r = 0; r < 16; ++r) mb[n * 16 + r] = acc[n][r];
        mb[32] = m;
        mb[33] = l;
    }
    __syncthreads();
    if (p == 0) {
        const float m1 = mb[32], l1 = mb[33];
        const float M = fmaxf(m, m1);
        const float sf0 = __builtin_amdgcn_exp2f(m - M);
        const float sf1 = __builtin_amdgcn_exp2f(m1 - M);
        const float linv = 1.0f / (sf0 * l + sf1 * l1);
        const int sw4 = rg & 3;
        #pragma unroll
        for (int n = 0; n < 2; ++n) {
            #pragma unroll
            for (int g = 0; g < 4; ++g) {
                #pragma unroll
                for (int e = 0; e < 4; e += 2) {
                    int r = 4 * g + e;
                    float o0 = (sf0 * acc[n][r]     + sf1 * mb[n * 16 + r])     * linv;
                    float o1 = (sf0 * acc[n][r + 1] + sf1 * mb[n * 16 + r + 1]) * linv;
                    unsigned pkv = pk_bf16(o0, o1);
                    int d = 32 * n + e + 8 * g + 4 * hi;
                    int col = hq * 64 + d;
                    int cp = ((col >> 3) & 3) ^ sw4;           // 32-col GEMM-A swizzle
                    *(unsigned*)(ob + (size_t)rg * 2048 + (col & ~31) + (cp << 3) + (col & 7)) = pkv;
                }
            }
        }
    }
}

// ---------------------------------------------------------------------------
extern "C" void kernel_launch(void* const* d_in, const int* in_sizes, int n_in,
                              void* d_out, int out_size, void* d_ws, size_t ws_size,
                              hipStream_t stream) {
    const float* x  = (const float*)d_in[0];
    const float* Wq = (const float*)d_in[1];
    const float* Wk = (const float*)d_in[2];
    const float* Wv = (const float*)d_in[3];
    const float* Wo = (const float*)d_in[4];
    const float* bo = (const float*)d_in[5];

    char* ws = (char*)d_ws;
    short* xb   = (short*)ws;                            // 8 MiB (reused as ob)
    short* wqkv = (short*)(ws + ((size_t)8  << 20));     // 12 MiB
    short* qb   = (short*)(ws + ((size_t)20 << 20));     // 8 MiB
    short* kb   = (short*)(ws + ((size_t)28 << 20));     // 2 MiB (attn-swizzled)
    short* vt   = (short*)(ws + ((size_t)30 << 20));     // 2 MiB (V^T, attn-swizzled)
    short* wob  = (short*)(ws + ((size_t)32 << 20));     // 8 MiB
    short* ob   = xb;      // x dead after QKV GEMM

    conv_all<<<7168, 256, 0, stream>>>(x, Wq, Wk, Wv, Wo, xb, wqkv, wob);
    gemm8<64, 0><<<dim3(48, 16), 512, 0, stream>>>(xb, wqkv, qb, kb, vt, nullptr, nullptr);
    attn_fwd<<<dim3(32, 16), 512, 0, stream>>>(qb, kb, vt, ob);
    gemm8<64, 1><<<dim3(32, 16), 512, 0, stream>>>(ob, wob, nullptr, nullptr, nullptr,
                                                   (float*)d_out, bo);
}

// Round 15
// 133.396 us; speedup vs baseline: 1.0322x; 1.0322x over previous
//
#include <hip/hip_runtime.h>
#include <hip/hip_bf16.h>

typedef __attribute__((ext_vector_type(8))) short short8;
typedef __attribute__((ext_vector_type(16))) float floatx16;
typedef __attribute__((ext_vector_type(4))) float floatx4;
typedef __attribute__((ext_vector_type(4))) unsigned uintx4;

__device__ __forceinline__ short f2bf(float f) {
    unsigned u = __builtin_bit_cast(unsigned, f);
    u += 0x7fffu + ((u >> 16) & 1u);   // RNE
    return (short)(u >> 16);
}

__device__ __forceinline__ unsigned pk_bf16(float lo, float hi) {
    unsigned short a = __builtin_bit_cast(unsigned short, (__bf16)lo);
    unsigned short b = __builtin_bit_cast(unsigned short, (__bf16)hi);
    return (unsigned)a | ((unsigned)b << 16);
}

__device__ __forceinline__ void gload_lds16(const void* g, void* l) {
    __builtin_amdgcn_global_load_lds(
        (const __attribute__((address_space(1))) unsigned*)g,
        (__attribute__((address_space(3))) unsigned*)l, 16, 0, 0);
}

// ---------------------------------------------------------------------------
// f32 -> bf16 convert for x, Wq/Wk/Wv, Wo — one launch. 64-col-tile XOR
// swizzle (GEMM operand layout): chunk cc of dest row holds src chunk cc^(row&7).
__global__ __launch_bounds__(256)
void conv_all(const float* __restrict__ x, const float* __restrict__ Wq,
              const float* __restrict__ Wk, const float* __restrict__ Wv,
              const float* __restrict__ Wo, short* __restrict__ xb,
              short* __restrict__ wqkv, short* __restrict__ wob) {
    const int bid = blockIdx.x;                // 0..7167
    const float* src; short* dst; int srow, drow;
    if (bid < 2048)      { src = x;  dst = xb;  srow = bid;        drow = bid; }
    else if (bid < 5120) {
        int r = bid - 2048;
        dst = wqkv; drow = r;
        if (r < 2048)      { src = Wq; srow = r; }
        else if (r < 2560) { src = Wk; srow = r - 2048; }
        else               { src = Wv; srow = r - 2560; }
    } else               { src = Wo; dst = wob; srow = bid - 5120; drow = srow; }
    const int c = threadIdx.x;
    const int kt = c >> 3, cc = c & 7;
    const float* s = src + (size_t)srow * 2048 + kt * 64 + (cc ^ (drow & 7)) * 8;
    float4 v0 = *(const float4*)s;
    float4 v1 = *(const float4*)(s + 4);
    short8 o = { f2bf(v0.x), f2bf(v0.y), f2bf(v0.z), f2bf(v0.w),
                 f2bf(v1.x), f2bf(v1.y), f2bf(v1.z), f2bf(v1.w) };
    *(short8*)(dst + (size_t)drow * 2048 + kt * 64 + cc * 8) = o;
}

// ---------------------------------------------------------------------------
// 4-wave double-buffered bf16 GEMM: BM=64, BN=64, BK=64, 256 threads.
// Wave-tile 32x32 (wm = w&1 row strip, wn = w>>1 col strip). 64-col XOR
// swizzle (chunk ^ (row&7)), LDS 32 KB -> 5 blocks/CU = 5 barrier domains.
// EPI 0: QKV epilogue (qb pre-scaled; kb/vt attn-swizzled). EPI 1: f32 + bias.
template<int EPI>
__global__ __launch_bounds__(256, 5)
void gemm4(const short* __restrict__ A, const short* __restrict__ Bw,
           short* __restrict__ qb, short* __restrict__ kb, short* __restrict__ vt,
           float* __restrict__ fout, const float* __restrict__ bias) {
    constexpr int K = 2048;
    constexpr int NIT = K / 64;
    __shared__ short sm[2][128 * 64];          // A 64x64 | B 64x64 per buf (16 KB)

    const int t = threadIdx.x, lane = t & 63, w = t >> 6;
    const int wm = w & 1, wn = w >> 1;
    const int l15 = lane & 15, lh = lane >> 4;
    const int bn = blockIdx.x, bm = blockIdx.y;
    const int ra0 = bm * 64;
    const short* Bbase = Bw + (size_t)bn * 64 * K;

    floatx4 acc[2][2] = {};

    auto stage = [&](int buf, int k0) {
        short* base = &sm[buf][0];
        #pragma unroll
        for (int i = 0; i < 4; ++i) {
            int c = i * 256 + t;
            if (c < 512) {                     // A chunks
                int row = c >> 3, cc = c & 7;
                gload_lds16(A + (size_t)(ra0 + row) * K + k0 + cc * 8, base + c * 8);
            } else {                           // B chunks
                int c2 = c - 512;
                int row = c2 >> 3, cc = c2 & 7;
                gload_lds16(Bbase + (size_t)row * K + k0 + cc * 8, base + c * 8);
            }
        }
    };

    stage(0, 0);
    #pragma unroll 1
    for (int it = 0; it < NIT; ++it) {
        __syncthreads();                       // slab `it` ready
        if (it + 1 < NIT) stage((it + 1) & 1, (it + 1) * 64);
        const short* As = &sm[it & 1][0];
        const short* Bs = As + 64 * 64;
        #pragma unroll
        for (int kf = 0; kf < 2; ++kf) {
            short8 a[2], b[2];
            #pragma unroll
            for (int m = 0; m < 2; ++m) {
                int arow = wm * 32 + m * 16 + l15;
                a[m] = *(const short8*)(As + arow * 64 + (((kf * 4 + lh) ^ (arow & 7)) << 3));
            }
            #pragma unroll
            for (int n = 0; n < 2; ++n) {
                int brow = wn * 32 + n * 16 + l15;
                b[n] = *(const short8*)(Bs + brow * 64 + (((kf * 4 + lh) ^ (brow & 7)) << 3));
            }
            #pragma unroll
            for (int m = 0; m < 2; ++m)
                #pragma unroll
                for (int n = 0; n < 2; ++n)
                    acc[m][n] = __builtin_amdgcn_mfma_f32_16x16x32_bf16(a[m], b[n], acc[m][n], 0, 0, 0);
        }
    }

    #pragma unroll
    for (int m = 0; m < 2; ++m) {
        #pragma unroll
        for (int n = 0; n < 2; ++n) {
            #pragma unroll
            for (int r = 0; r < 4; ++r) {
                int row = ra0 + wm * 32 + m * 16 + lh * 4 + r;
                int col = bn * 64 + wn * 32 + n * 16 + l15;
                float v = acc[m][n][r];
                if constexpr (EPI == 1) {
                    fout[(size_t)row * 2048 + col] = v + bias[col];
                } else {
                    if (col < 2048) {
                        qb[(size_t)row * 2048 + col] = f2bf(v * 0.18033688011112042f);
                    } else if (col < 2560) {
                        int kcol = col - 2048, within = kcol & 63;
                        int cp = ((within >> 3) ^ (row & 7)) & 7;
                        kb[(size_t)row * 512 + (kcol & ~63) + (cp << 3) + (within & 7)] = f2bf(v);
                    } else {
                        int dg = col - 2560;
                        int cp = (((row >> 3) & 7) ^ (dg & 7)) & 7;
                        vt[(size_t)dg * 2048 + (row & ~63) + (cp << 3) + (row & 7)] = f2bf(v);
                    }
                }
            }
        }
    }
}

// ---------------------------------------------------------------------------
// Causal GQA attention (round-13 proven kernel, byte-identical): 8 waves =
// 4 q-strips {A0,A1,B0,B1} x kv-parity; pair {i, 31-i}; 128-kv-row slabs
// double-buffered; one barrier per slab; parity partials merged via LDS.
// hq = blockIdx.x -> linear id % 8 == hq % 8 (XCD-local KV, L2-resident).
__global__ __launch_bounds__(512, 4)
void attn_fwd(const short* __restrict__ qb, const short* __restrict__ kb,
              const short* __restrict__ vt, short* __restrict__ ob) {
    __shared__ __align__(16) short smem[2][16384];  // per buf: K 128x64 | V^T 64x128

    const int t = threadIdx.x, lane = t & 63, w = t >> 6;
    const int l31 = lane & 31, hi = lane >> 5;
    const int hq = blockIdx.x, hk = hq >> 2;   // XCD-local head placement
    const int pairi = blockIdx.y;              // 0..15
    const int qtA = pairi, qtB = 31 - pairi;
    const int a = w >> 1, p = w & 1;           // strip 0..3, kv parity
    const int s = a & 1;
    const int myqt = (a < 2) ? qtA : qtB;
    const int q0 = myqt * 64 + s * 32;
    const int rg = q0 + l31;                   // this lane's q row
    const int swl = l31 & 7;

    short8 qf[4];
    {
        const short* qrow = qb + (size_t)rg * 2048 + hq * 64;
        #pragma unroll
        for (int kk = 0; kk < 4; ++kk)
            qf[kk] = *(const short8*)(qrow + kk * 16 + hi * 8);
    }

    float m = -3e38f, l = 0.f;
    floatx16 acc[2] = {};

    auto stage = [&](int buf, int j0) {        // j0 = slab base kv-row
        short* base = &smem[buf][0];
        #pragma unroll
        for (int i = 0; i < 4; ++i) {
            int c = i * 512 + t;
            if (i < 2) {                       // K chunks 0..1023
                int row = c >> 3, cc = c & 7;
                gload_lds16(kb + (size_t)(j0 + row) * 512 + hk * 64 + cc * 8, base + c * 8);
            } else {                           // V chunks 1024..2047
                int cv = c - 1024, drow = cv >> 4, cc = cv & 15;
                gload_lds16(vt + (size_t)(hk * 64 + drow) * 2048 + j0 + cc * 8, base + c * 8);
            }
        }
    };

    const int nss = (qtB >> 1) + 1;
    stage(0, 0);
    #pragma unroll 1
    for (int ss = 0; ss < nss; ++ss) {
        __syncthreads();                       // slab ss ready
        if (ss + 1 < nss) stage((ss + 1) & 1, (ss + 1) * 128);
        const int kt = 2 * ss + p;
        if (kt <= myqt) {
            const short* K0 = &smem[ss & 1][0];
            const short* V0 = &smem[ss & 1][8192];

            // ---- S^T = K . Q^T (2 kv-blocks x 4 k-steps)
            floatx16 sT[2];
            #pragma unroll
            for (int kb2 = 0; kb2 < 2; ++kb2) {
                floatx16 acc2 = {};
                const int row = p * 64 + kb2 * 32 + l31;
                #pragma unroll
                for (int kk = 0; kk < 4; ++kk) {
                    short8 kf = *(const short8*)(K0 + row * 64 + (((2 * kk + hi) ^ swl) << 3));
                    acc2 = __builtin_amdgcn_mfma_f32_32x32x16_bf16(kf, qf[kk], acc2, 0, 0, 0);
                }
                sT[kb2] = acc2;
            }

            // ---- causal mask (diagonal tile only)
            if (kt == myqt) {
                #pragma unroll
                for (int kb2 = 0; kb2 < 2; ++kb2)
                    #pragma unroll
                    for (int r = 0; r < 16; ++r) {
                        int jg = kt * 64 + kb2 * 32 + (r & 3) + 8 * (r >> 2) + 4 * hi;
                        if (jg > rg) sT[kb2][r] = -3e38f;
                    }
            }

            // ---- row max
            float v[16];
            #pragma unroll
            for (int r = 0; r < 16; ++r) v[r] = fmaxf(sT[0][r], sT[1][r]);
            #pragma unroll
            for (int st = 8; st >= 1; st >>= 1)
                #pragma unroll
                for (int r = 0; r < 8; ++r)
                    if (r < st) v[r] = fmaxf(v[r], v[r + st]);
            float tm = fmaxf(v[0], __shfl_xor(v[0], 32));

            // ---- defer-max
            if (!__all(tm <= m + 8.0f)) {
                float mn = fmaxf(m, tm);
                float sf = __builtin_amdgcn_exp2f(m - mn);
                m = mn;
                l *= sf;
                #pragma unroll
                for (int n = 0; n < 2; ++n)
                    #pragma unroll
                    for (int r = 0; r < 16; ++r) acc[n][r] *= sf;
            }

            // ---- p = exp2(s - m), row sum
            float sv[16];
            #pragma unroll
            for (int kb2 = 0; kb2 < 2; ++kb2)
                #pragma unroll
                for (int r = 0; r < 16; ++r)
                    sT[kb2][r] = __builtin_amdgcn_exp2f(sT[kb2][r] - m);
            #pragma unroll
            for (int r = 0; r < 16; ++r) sv[r] = sT[0][r] + sT[1][r];
            #pragma unroll
            for (int st = 8; st >= 1; st >>= 1)
                #pragma unroll
                for (int r = 0; r < 8; ++r)
                    if (r < st) sv[r] += sv[r + st];
            l += sv[0] + __shfl_xor(sv[0], 32);

            // ---- P^T -> B-fragments (cvt_pk + cross-half exchange), then PV
            #pragma unroll
            for (int kb2 = 0; kb2 < 2; ++kb2) {
                unsigned Qd[8], Pd[8];
                #pragma unroll
                for (int c = 0; c < 8; ++c)
                    Qd[c] = pk_bf16(sT[kb2][2 * c], sT[kb2][2 * c + 1]);
                #pragma unroll
                for (int c = 0; c < 8; ++c)
                    Pd[c] = __shfl_xor(Qd[c], 32);
                #pragma unroll
                for (int b = 0; b < 2; ++b) {
                    uintx4 j;
                    if (b == 0) {
                        j.x = hi ? Pd[2] : Qd[0];
                        j.y = hi ? Pd[3] : Qd[1];
                        j.z = hi ? Qd[2] : Pd[0];
                        j.w = hi ? Qd[3] : Pd[1];
                    } else {
                        j.x = hi ? Pd[6] : Qd[4];
                        j.y = hi ? Pd[7] : Qd[5];
                        j.z = hi ? Qd[6] : Pd[4];
                        j.w = hi ? Qd[7] : Pd[5];
                    }
                    short8 pf = __builtin_bit_cast(short8, j);
                    const int kk = kb2 * 2 + b;
                    const int ch = p * 64 + (((2 * kk + hi) ^ swl) << 3);
                    short8 vf0 = *(const short8*)(V0 + l31 * 128 + ch);
                    acc[0] = __builtin_amdgcn_mfma_f32_32x32x16_bf16(vf0, pf, acc[0], 0, 0, 0);
                    short8 vf1 = *(const short8*)(V0 + (32 + l31) * 128 + ch);
                    acc[1] = __builtin_amdgcn_mfma_f32_32x32x16_bf16(vf1, pf, acc[1], 0, 0, 0);
                }
            }
        }
    }

    // ---- merge the two kv-parity partials per strip (lane = q column)
    __syncthreads();                           // all compute done; reuse smem
    float* mb = (float*)&smem[0][0] + ((size_t)a * 64 + lane) * 34;
    if (p == 1) {
        #pragma unroll
        for (int n = 0; n < 2; ++n)
            #pragma unroll
            for (int r = 0; r < 16; ++r) mb[n * 16 + r] = acc[n][r];
        mb[32] = m;
        mb[33] = l;
    }
    __syncthreads();
    if (p == 0) {
        const float m1 = mb[32], l1 = mb[33];
        const float M = fmaxf(m, m1);
        const float sf0 = __builtin_amdgcn_exp2f(m - M);
        const float sf1 = __builtin_amdgcn_exp2f(m1 - M);
        const float linv = 1.0f / (sf0 * l + sf1 * l1);
        const int sw8 = rg & 7;
        #pragma unroll
        for (int n = 0; n < 2; ++n) {
            #pragma unroll
            for (int g = 0; g < 4; ++g) {
                #pragma unroll
                for (int e = 0; e < 4; e += 2) {
                    int r = 4 * g + e;
                    float o0 = (sf0 * acc[n][r]     + sf1 * mb[n * 16 + r])     * linv;
                    float o1 = (sf0 * acc[n][r + 1] + sf1 * mb[n * 16 + r + 1]) * linv;
                    unsigned pkv = pk_bf16(o0, o1);
                    int d = 32 * n + e + 8 * g + 4 * hi;
                    int col = hq * 64 + d;
                    int cp = ((col >> 3) & 7) ^ sw8;           // 64-col GEMM-A swizzle
                    *(unsigned*)(ob + (size_t)rg * 2048 + (col & ~63) + (cp << 3) + (col & 7)) = pkv;
                }
            }
        }
    }
}

// ---------------------------------------------------------------------------
extern "C" void kernel_launch(void* const* d_in, const int* in_sizes, int n_in,
                              void* d_out, int out_size, void* d_ws, size_t ws_size,
                              hipStream_t stream) {
    const float* x  = (const float*)d_in[0];
    const float* Wq = (const float*)d_in[1];
    const float* Wk = (const float*)d_in[2];
    const float* Wv = (const float*)d_in[3];
    const float* Wo = (const float*)d_in[4];
    const float* bo = (const float*)d_in[5];

    char* ws = (char*)d_ws;
    short* xb   = (short*)ws;                            // 8 MiB (reused as ob)
    short* wqkv = (short*)(ws + ((size_t)8  << 20));     // 12 MiB
    short* qb   = (short*)(ws + ((size_t)20 << 20));     // 8 MiB
    short* kb   = (short*)(ws + ((size_t)28 << 20));     // 2 MiB (attn-swizzled)
    short* vt   = (short*)(ws + ((size_t)30 << 20));     // 2 MiB (V^T, attn-swizzled)
    short* wob  = (short*)(ws + ((size_t)32 << 20));     // 8 MiB
    short* ob   = xb;      // x dead after QKV GEMM

    conv_all<<<7168, 256, 0, stream>>>(x, Wq, Wk, Wv, Wo, xb, wqkv, wob);
    gemm4<0><<<dim3(48, 32), 256, 0, stream>>>(xb, wqkv, qb, kb, vt, nullptr, nullptr);
    attn_fwd<<<dim3(32, 16), 512, 0, stream>>>(qb, kb, vt, ob);
    gemm4<1><<<dim3(32, 32), 256, 0, stream>>>(ob, wob, nullptr, nullptr, nullptr,
                                               (float*)d_out, bo);
}

// Round 16
// 117.749 us; speedup vs baseline: 1.1694x; 1.1329x over previous
//
#include <hip/hip_runtime.h>
#include <hip/hip_bf16.h>

typedef __attribute__((ext_vector_type(8))) short short8;
typedef __attribute__((ext_vector_type(16))) float floatx16;
typedef __attribute__((ext_vector_type(4))) float floatx4;
typedef __attribute__((ext_vector_type(4))) unsigned uintx4;

__device__ __forceinline__ short f2bf(float f) {
    unsigned u = __builtin_bit_cast(unsigned, f);
    u += 0x7fffu + ((u >> 16) & 1u);   // RNE
    return (short)(u >> 16);
}

__device__ __forceinline__ unsigned pk_bf16(float lo, float hi) {
    unsigned short a = __builtin_bit_cast(unsigned short, (__bf16)lo);
    unsigned short b = __builtin_bit_cast(unsigned short, (__bf16)hi);
    return (unsigned)a | ((unsigned)b << 16);
}

__device__ __forceinline__ void gload_lds16(const void* g, void* l) {
    __builtin_amdgcn_global_load_lds(
        (const __attribute__((address_space(1))) unsigned*)g,
        (__attribute__((address_space(3))) unsigned*)l, 16, 0, 0);
}

// ---------------------------------------------------------------------------
// f32 -> bf16 convert for x, Wq/Wk/Wv, Wo — one launch. 64-col-tile XOR
// swizzle (GEMM operand layout): chunk cc of dest row holds src chunk cc^(row&7).
__global__ __launch_bounds__(256)
void conv_all(const float* __restrict__ x, const float* __restrict__ Wq,
              const float* __restrict__ Wk, const float* __restrict__ Wv,
              const float* __restrict__ Wo, short* __restrict__ xb,
              short* __restrict__ wqkv, short* __restrict__ wob) {
    const int bid = blockIdx.x;                // 0..7167
    const float* src; short* dst; int srow, drow;
    if (bid < 2048)      { src = x;  dst = xb;  srow = bid;        drow = bid; }
    else if (bid < 5120) {
        int r = bid - 2048;
        dst = wqkv; drow = r;
        if (r < 2048)      { src = Wq; srow = r; }
        else if (r < 2560) { src = Wk; srow = r - 2048; }
        else               { src = Wv; srow = r - 2560; }
    } else               { src = Wo; dst = wob; srow = bid - 5120; drow = srow; }
    const int c = threadIdx.x;
    const int kt = c >> 3, cc = c & 7;
    const float* s = src + (size_t)srow * 2048 + kt * 64 + (cc ^ (drow & 7)) * 8;
    float4 v0 = *(const float4*)s;
    float4 v1 = *(const float4*)(s + 4);
    short8 o = { f2bf(v0.x), f2bf(v0.y), f2bf(v0.z), f2bf(v0.w),
                 f2bf(v1.x), f2bf(v1.y), f2bf(v1.z), f2bf(v1.w) };
    *(short8*)(dst + (size_t)drow * 2048 + kt * 64 + cc * 8) = o;
}

// ---------------------------------------------------------------------------
// 8-wave double-buffered bf16 GEMM (round-8/11 proven structure).
// EPI 0: QKV epilogue (qb pre-scaled; kb/vt attn-swizzled). EPI 1: f32 + bias.
template<int BN, int EPI>
__global__ __launch_bounds__(512, 4)
void gemm8(const short* __restrict__ A, const short* __restrict__ Bw,
           short* __restrict__ qb, short* __restrict__ kb, short* __restrict__ vt,
           float* __restrict__ fout, const float* __restrict__ bias) {
    constexpr int K = 2048;
    constexpr int NN = BN / 32;
    constexpr int ACH = 128 * 8;
    constexpr int NCH = (128 + BN) * 8;
    constexpr int NIT = K / 64;
    __shared__ short sm[2][(128 + BN) * 64];

    const int t = threadIdx.x, lane = t & 63, w = t >> 6;
    const int wm = w & 3, wn = w >> 2;
    const int l15 = lane & 15, lh = lane >> 4;
    const int bn = blockIdx.x, bm = blockIdx.y;
    const int ra0 = bm * 128;
    const short* Bbase = Bw + (size_t)bn * BN * K;

    floatx4 acc[2][NN] = {};

    auto stage = [&](int buf, int k0) {
        short* base = &sm[buf][0];
        #pragma unroll
        for (int i = 0; i < NCH / 512; ++i) {
            int c = i * 512 + t;
            if (c < ACH) {
                int row = c >> 3, cc = c & 7;
                gload_lds16(A + (size_t)(ra0 + row) * K + k0 + cc * 8, base + c * 8);
            } else {
                int c2 = c - ACH;
                int row = c2 >> 3, cc = c2 & 7;
                gload_lds16(Bbase + (size_t)row * K + k0 + cc * 8, base + (ACH + c2) * 8);
            }
        }
    };

    stage(0, 0);
    #pragma unroll 1
    for (int it = 0; it < NIT; ++it) {
        __syncthreads();                       // slab `it` ready
        if (it + 1 < NIT) stage((it + 1) & 1, (it + 1) * 64);
        const short* As = &sm[it & 1][0];
        const short* Bs = As + 128 * 64;
        #pragma unroll
        for (int kf = 0; kf < 2; ++kf) {
            short8 a[2], b[NN];
            #pragma unroll
            for (int m = 0; m < 2; ++m) {
                int arow = wm * 32 + m * 16 + l15;
                a[m] = *(const short8*)(As + arow * 64 + (((kf * 4 + lh) ^ (arow & 7)) << 3));
            }
            #pragma unroll
            for (int n = 0; n < NN; ++n) {
                int brow = wn * (BN / 2) + n * 16 + l15;
                b[n] = *(const short8*)(Bs + brow * 64 + (((kf * 4 + lh) ^ (brow & 7)) << 3));
            }
            #pragma unroll
            for (int m = 0; m < 2; ++m)
                #pragma unroll
                for (int n = 0; n < NN; ++n)
                    acc[m][n] = __builtin_amdgcn_mfma_f32_16x16x32_bf16(a[m], b[n], acc[m][n], 0, 0, 0);
        }
    }

    #pragma unroll
    for (int m = 0; m < 2; ++m) {
        #pragma unroll
        for (int n = 0; n < NN; ++n) {
            #pragma unroll
            for (int r = 0; r < 4; ++r) {
                int row = ra0 + wm * 32 + m * 16 + lh * 4 + r;
                int col = bn * BN + wn * (BN / 2) + n * 16 + l15;
                float v = acc[m][n][r];
                if constexpr (EPI == 1) {
                    fout[(size_t)row * 2048 + col] = v + bias[col];
                } else {
                    if (col < 2048) {
                        qb[(size_t)row * 2048 + col] = f2bf(v * 0.18033688011112042f);
                    } else if (col < 2560) {
                        int kcol = col - 2048, within = kcol & 63;
                        int cp = ((within >> 3) ^ (row & 7)) & 7;
                        kb[(size_t)row * 512 + (kcol & ~63) + (cp << 3) + (within & 7)] = f2bf(v);
                    } else {
                        int dg = col - 2560;
                        int cp = (((row >> 3) & 7) ^ (dg & 7)) & 7;
                        vt[(size_t)dg * 2048 + (row & ~63) + (cp << 3) + (row & 7)] = f2bf(v);
                    }
                }
            }
        }
    }
}

// ---------------------------------------------------------------------------
// Causal GQA attention (proven kernel): 8 waves = 4 q-strips {A0,A1,B0,B1}
// x kv-parity; pair {i, 31-i}; 128-kv-row slabs double-buffered; one barrier
// per slab; parity partials merged via LDS. hq = blockIdx.x -> linear
// id % 8 == hq % 8 (XCD-local KV, L2-resident).
__global__ __launch_bounds__(512, 4)
void attn_fwd(const short* __restrict__ qb, const short* __restrict__ kb,
              const short* __restrict__ vt, short* __restrict__ ob) {
    __shared__ __align__(16) short smem[2][16384];  // per buf: K 128x64 | V^T 64x128

    const int t = threadIdx.x, lane = t & 63, w = t >> 6;
    const int l31 = lane & 31, hi = lane >> 5;
    const int hq = blockIdx.x, hk = hq >> 2;   // XCD-local head placement
    const int pairi = blockIdx.y;              // 0..15
    const int qtA = pairi, qtB = 31 - pairi;
    const int a = w >> 1, p = w & 1;           // strip 0..3, kv parity
    const int s = a & 1;
    const int myqt = (a < 2) ? qtA : qtB;
    const int q0 = myqt * 64 + s * 32;
    const int rg = q0 + l31;                   // this lane's q row
    const int swl = l31 & 7;

    short8 qf[4];
    {
        const short* qrow = qb + (size_t)rg * 2048 + hq * 64;
        #pragma unroll
        for (int kk = 0; kk < 4; ++kk)
            qf[kk] = *(const short8*)(qrow + kk * 16 + hi * 8);
    }

    float m = -3e38f, l = 0.f;
    floatx16 acc[2] = {};

    auto stage = [&](int buf, int j0) {        // j0 = slab base kv-row
        short* base = &smem[buf][0];
        #pragma unroll
        for (int i = 0; i < 4; ++i) {
            int c = i * 512 + t;
            if (i < 2) {                       // K chunks 0..1023
                int row = c >> 3, cc = c & 7;
                gload_lds16(kb + (size_t)(j0 + row) * 512 + hk * 64 + cc * 8, base + c * 8);
            } else {                           // V chunks 1024..2047
                int cv = c - 1024, drow = cv >> 4, cc = cv & 15;
                gload_lds16(vt + (size_t)(hk * 64 + drow) * 2048 + j0 + cc * 8, base + c * 8);
            }
        }
    };

    const int nss = (qtB >> 1) + 1;
    stage(0, 0);
    #pragma unroll 1
    for (int ss = 0; ss < nss; ++ss) {
        __syncthreads();                       // slab ss ready
        if (ss + 1 < nss) stage((ss + 1) & 1, (ss + 1) * 128);
        const int kt = 2 * ss + p;
        if (kt <= myqt) {
            const short* K0 = &smem[ss & 1][0];
            const short* V0 = &smem[ss & 1][8192];

            // ---- S^T = K . Q^T (2 kv-blocks x 4 k-steps)
            floatx16 sT[2];
            #pragma unroll
            for (int kb2 = 0; kb2 < 2; ++kb2) {
                floatx16 acc2 = {};
                const int row = p * 64 + kb2 * 32 + l31;
                #pragma unroll
                for (int kk = 0; kk < 4; ++kk) {
                    short8 kf = *(const short8*)(K0 + row * 64 + (((2 * kk + hi) ^ swl) << 3));
                    acc2 = __builtin_amdgcn_mfma_f32_32x32x16_bf16(kf, qf[kk], acc2, 0, 0, 0);
                }
                sT[kb2] = acc2;
            }

            // ---- causal mask (diagonal tile only)
            if (kt == myqt) {
                #pragma unroll
                for (int kb2 = 0; kb2 < 2; ++kb2)
                    #pragma unroll
                    for (int r = 0; r < 16; ++r) {
                        int jg = kt * 64 + kb2 * 32 + (r & 3) + 8 * (r >> 2) + 4 * hi;
                        if (jg > rg) sT[kb2][r] = -3e38f;
                    }
            }

            // ---- row max
            float v[16];
            #pragma unroll
            for (int r = 0; r < 16; ++r) v[r] = fmaxf(sT[0][r], sT[1][r]);
            #pragma unroll
            for (int st = 8; st >= 1; st >>= 1)
                #pragma unroll
                for (int r = 0; r < 8; ++r)
                    if (r < st) v[r] = fmaxf(v[r], v[r + st]);
            float tm = fmaxf(v[0], __shfl_xor(v[0], 32));

            // ---- defer-max
            if (!__all(tm <= m + 8.0f)) {
                float mn = fmaxf(m, tm);
                float sf = __builtin_amdgcn_exp2f(m - mn);
                m = mn;
                l *= sf;
                #pragma unroll
                for (int n = 0; n < 2; ++n)
                    #pragma unroll
                    for (int r = 0; r < 16; ++r) acc[n][r] *= sf;
            }

            // ---- p = exp2(s - m), row sum
            float sv[16];
            #pragma unroll
            for (int kb2 = 0; kb2 < 2; ++kb2)
                #pragma unroll
                for (int r = 0; r < 16; ++r)
                    sT[kb2][r] = __builtin_amdgcn_exp2f(sT[kb2][r] - m);
            #pragma unroll
            for (int r = 0; r < 16; ++r) sv[r] = sT[0][r] + sT[1][r];
            #pragma unroll
            for (int st = 8; st >= 1; st >>= 1)
                #pragma unroll
                for (int r = 0; r < 8; ++r)
                    if (r < st) sv[r] += sv[r + st];
            l += sv[0] + __shfl_xor(sv[0], 32);

            // ---- P^T -> B-fragments (cvt_pk + cross-half exchange), then PV
            #pragma unroll
            for (int kb2 = 0; kb2 < 2; ++kb2) {
                unsigned Qd[8], Pd[8];
                #pragma unroll
                for (int c = 0; c < 8; ++c)
                    Qd[c] = pk_bf16(sT[kb2][2 * c], sT[kb2][2 * c + 1]);
                #pragma unroll
                for (int c = 0; c < 8; ++c)
                    Pd[c] = __shfl_xor(Qd[c], 32);
                #pragma unroll
                for (int b = 0; b < 2; ++b) {
                    uintx4 j;
                    if (b == 0) {
                        j.x = hi ? Pd[2] : Qd[0];
                        j.y = hi ? Pd[3] : Qd[1];
                        j.z = hi ? Qd[2] : Pd[0];
                        j.w = hi ? Qd[3] : Pd[1];
                    } else {
                        j.x = hi ? Pd[6] : Qd[4];
                        j.y = hi ? Pd[7] : Qd[5];
                        j.z = hi ? Qd[6] : Pd[4];
                        j.w = hi ? Qd[7] : Pd[5];
                    }
                    short8 pf = __builtin_bit_cast(short8, j);
                    const int kk = kb2 * 2 + b;
                    const int ch = p * 64 + (((2 * kk + hi) ^ swl) << 3);
                    short8 vf0 = *(const short8*)(V0 + l31 * 128 + ch);
                    acc[0] = __builtin_amdgcn_mfma_f32_32x32x16_bf16(vf0, pf, acc[0], 0, 0, 0);
                    short8 vf1 = *(const short8*)(V0 + (32 + l31) * 128 + ch);
                    acc[1] = __builtin_amdgcn_mfma_f32_32x32x16_bf16(vf1, pf, acc[1], 0, 0, 0);
                }
            }
        }
    }

    // ---- merge the two kv-parity partials per strip (lane = q column)
    __syncthreads();                           // all compute done; reuse smem
    float* mb = (float*)&smem[0][0] + ((size_t)a * 64 + lane) * 34;
    if (p == 1) {
        #pragma unroll
        for (int n = 0; n < 2; ++n)
            #pragma unroll
            for (int r = 0; r < 16; ++r) mb[n * 16 + r] = acc[n][r];
        mb[32] = m;
        mb[33] = l;
    }
    __syncthreads();
    if (p == 0) {
        const float m1 = mb[32], l1 = mb[33];
        const float M = fmaxf(m, m1);
        const float sf0 = __builtin_amdgcn_exp2f(m - M);
        const float sf1 = __builtin_amdgcn_exp2f(m1 - M);
        const float linv = 1.0f / (sf0 * l + sf1 * l1);
        const int sw8 = rg & 7;
        #pragma unroll
        for (int n = 0; n < 2; ++n) {
            #pragma unroll
            for (int g = 0; g < 4; ++g) {
                #pragma unroll
                for (int e = 0; e < 4; e += 2) {
                    int r = 4 * g + e;
                    float o0 = (sf0 * acc[n][r]     + sf1 * mb[n * 16 + r])     * linv;
                    float o1 = (sf0 * acc[n][r + 1] + sf1 * mb[n * 16 + r + 1]) * linv;
                    unsigned pkv = pk_bf16(o0, o1);
                    int d = 32 * n + e + 8 * g + 4 * hi;
                    int col = hq * 64 + d;
                    int cp = ((col >> 3) & 7) ^ sw8;           // 64-col GEMM-A swizzle
                    *(unsigned*)(ob + (size_t)rg * 2048 + (col & ~63) + (cp << 3) + (col & 7)) = pkv;
                }
            }
        }
    }
}

// ---------------------------------------------------------------------------
extern "C" void kernel_launch(void* const* d_in, const int* in_sizes, int n_in,
                              void* d_out, int out_size, void* d_ws, size_t ws_size,
                              hipStream_t stream) {
    const float* x  = (const float*)d_in[0];
    const float* Wq = (const float*)d_in[1];
    const float* Wk = (const float*)d_in[2];
    const float* Wv = (const float*)d_in[3];
    const float* Wo = (const float*)d_in[4];
    const float* bo = (const float*)d_in[5];

    char* ws = (char*)d_ws;
    short* xb   = (short*)ws;                            // 8 MiB (reused as ob)
    short* wqkv = (short*)(ws + ((size_t)8  << 20));     // 12 MiB
    short* qb   = (short*)(ws + ((size_t)20 << 20));     // 8 MiB
    short* kb   = (short*)(ws + ((size_t)28 << 20));     // 2 MiB (attn-swizzled)
    short* vt   = (short*)(ws + ((size_t)30 << 20));     // 2 MiB (V^T, attn-swizzled)
    short* wob  = (short*)(ws + ((size_t)32 << 20));     // 8 MiB
    short* ob   = xb;      // x dead after QKV GEMM

    conv_all<<<7168, 256, 0, stream>>>(x, Wq, Wk, Wv, Wo, xb, wqkv, wob);
    gemm8<128, 0><<<dim3(24, 16), 512, 0, stream>>>(xb, wqkv, qb, kb, vt, nullptr, nullptr);
    attn_fwd<<<dim3(32, 16), 512, 0, stream>>>(qb, kb, vt, ob);
    gemm8<64, 1><<<dim3(32, 16), 512, 0, stream>>>(ob, wob, nullptr, nullptr, nullptr,
                                                   (float*)d_out, bo);
}